// Round 9
// baseline (335.240 us; speedup 1.0000x reference)
//
#include <hip/hip_runtime.h>
#include <math.h>

namespace {

constexpr int kB = 512, kI = 1152, kD = 8, kJ = 10, kC = 16;
constexpr int THREADS = 1024;               // 16 waves -> 50% occupancy at 1 block/CU
constexpr int TB = 2;                       // batches per block (shares W loads)
constexpr int GRP = THREADS / 8;            // 128 i-groups; 8 threads (c8) per i
constexpr int ROWS = kI / GRP;              // 9 rows per thread
constexpr int NW = THREADS / 64;            // 16 waves
constexpr float EPS = 1e-7f;

// Thread (g = t>>3, c8 = t&7) owns i-rows {g + 128*r} and channels {2c8, 2c8+1}.
// x_hat lives in LDS in exactly this layout (no transpose); all LDS access is
// float2/float4 on linear addresses -> conflict-free.
//
// vs round 8 (208 us, 8 waves, latency-bound):
//  - 1024 threads: same block count / same W L2-traffic, double the waves.
//  - softmax max-subtraction REMOVED: b_i starts at 0 and |b_i| < 6 always
//    (|v|<1 from squash, |xhat_i| ~ O(1)), so exp cannot overflow and softmax
//    is shift-invariant; kills one barrier + one block-reduction per iter.
//  - parity double-buffered sred scratch -> 1 barrier per routing iteration.
__launch_bounds__(THREADS)
__global__ void digitcaps_fused(const float* __restrict__ x,
                                const float* __restrict__ W,
                                float* __restrict__ out) {
  __shared__ float xhat[TB][kI][kC];        // 147,456 B
  __shared__ float sredS[2][TB][NW][kC];    // 8,192 B (parity-buffered)
  __shared__ float sredZ[2][TB][NW];        // 512 B

  const int t    = threadIdx.x;
  const int lane = t & 63;
  const int wid  = t >> 6;
  const int c8   = t & 7;                   // channel pair {2c8, 2c8+1}
  const int g    = t >> 3;                  // i-group 0..127

  const int bid = blockIdx.x;
  const int j   = bid >> 8;                 // j-major: 256 blocks share W[j] in L2
  const int b0  = (bid & 255) * TB;

  // ---------------- Phase 1: x_hat[b,j,i,c] = sum_d x[b,i,d]*W[j,i,d,c] -----
  #pragma unroll 3
  for (int it = 0; it < ROWS; ++it) {
    const int i = it * GRP + g;
    const float* Wp = W + (size_t)(j * kI + i) * (kD * kC) + (c8 << 1);
    float xr[TB][kD];
    #pragma unroll
    for (int tb = 0; tb < TB; ++tb) {
      const float4* xp = reinterpret_cast<const float4*>(
          x + (size_t)((b0 + tb) * kI + i) * kD);
      const float4 v0 = xp[0], v1 = xp[1];
      xr[tb][0] = v0.x; xr[tb][1] = v0.y; xr[tb][2] = v0.z; xr[tb][3] = v0.w;
      xr[tb][4] = v1.x; xr[tb][5] = v1.y; xr[tb][6] = v1.z; xr[tb][7] = v1.w;
    }
    float a0[TB] = {}, a1[TB] = {};
    #pragma unroll
    for (int d = 0; d < kD; ++d) {
      const float2 w = *reinterpret_cast<const float2*>(Wp + d * kC);
      #pragma unroll
      for (int tb = 0; tb < TB; ++tb) {
        a0[tb] += xr[tb][d] * w.x;
        a1[tb] += xr[tb][d] * w.y;
      }
    }
    #pragma unroll
    for (int tb = 0; tb < TB; ++tb) {
      float2 v2; v2.x = a0[tb]; v2.y = a1[tb];
      *reinterpret_cast<float2*>(&xhat[tb][i][c8 * 2]) = v2;
    }
  }
  __syncthreads();                          // phase-1 -> phase-2

  // ---------------- Phase 2: 3 routing iterations, 1 barrier each -----------
  float bl[TB][ROWS];                       // logits; identical across c8 lanes
  #pragma unroll
  for (int tb = 0; tb < TB; ++tb)
    #pragma unroll
    for (int r = 0; r < ROWS; ++r) bl[tb][r] = 0.f;

  #pragma unroll
  for (int itr = 0; itr < 3; ++itr) {
    const int p = itr & 1;

    // --- partial Z and s over own rows/channels (no max needed) ---
    float zp[TB], sp0[TB], sp1[TB];
    #pragma unroll
    for (int tb = 0; tb < TB; ++tb) {
      zp[tb] = 0.f; sp0[tb] = 0.f; sp1[tb] = 0.f;
      #pragma unroll
      for (int r = 0; r < ROWS; ++r) {
        const int i = r * GRP + g;
        const float2 h = *reinterpret_cast<const float2*>(&xhat[tb][i][c8 * 2]);
        const float e = expf(bl[tb][r]);
        zp[tb]  += e;
        sp0[tb] += e * h.x;
        sp1[tb] += e * h.y;
      }
    }
    #pragma unroll
    for (int off = 8; off < 64; off <<= 1) {          // reduce over g in wave
      #pragma unroll
      for (int tb = 0; tb < TB; ++tb) {
        zp[tb]  += __shfl_xor(zp[tb],  off, 64);
        sp0[tb] += __shfl_xor(sp0[tb], off, 64);
        sp1[tb] += __shfl_xor(sp1[tb], off, 64);
      }
    }
    if (lane < 8) {                                   // lane == c8 here
      #pragma unroll
      for (int tb = 0; tb < TB; ++tb) {
        float2 v2; v2.x = sp0[tb]; v2.y = sp1[tb];
        *reinterpret_cast<float2*>(&sredS[p][tb][wid][lane * 2]) = v2;
      }
    }
    if (lane == 0) {
      #pragma unroll
      for (int tb = 0; tb < TB; ++tb) sredZ[p][tb][wid] = zp[tb];
    }
    __syncthreads();                                  // the iteration's barrier

    // --- combine wave partials; squash; agreement or final write ---
    #pragma unroll
    for (int tb = 0; tb < TB; ++tb) {
      float Z = 0.f;
      #pragma unroll
      for (int w = 0; w < NW; ++w) Z += sredZ[p][tb][w];
      float s0 = 0.f, s1 = 0.f;
      #pragma unroll
      for (int w = 0; w < NW; ++w) {                  // broadcast reads
        const float2 v2 = *reinterpret_cast<const float2*>(&sredS[p][tb][w][c8 * 2]);
        s0 += v2.x; s1 += v2.y;
      }
      const float invZ = 1.f / Z;
      s0 *= invZ; s1 *= invZ;
      float pq = s0 * s0 + s1 * s1;
      pq += __shfl_xor(pq, 1, 64);                    // sum |s|^2 across c8
      pq += __shfl_xor(pq, 2, 64);
      pq += __shfl_xor(pq, 4, 64);
      const float nrm = sqrtf(pq);
      const float fac = pq / ((1.f + pq) * (nrm + EPS));

      if (itr < 2) {
        const float vc0 = fac * s0, vc1 = fac * s1;
        #pragma unroll
        for (int r = 0; r < ROWS; ++r) {
          const int i = r * GRP + g;
          const float2 h = *reinterpret_cast<const float2*>(&xhat[tb][i][c8 * 2]);
          float dp = vc0 * h.x + vc1 * h.y;
          dp += __shfl_xor(dp, 1, 64);                // sum across c8 (same g)
          dp += __shfl_xor(dp, 2, 64);
          dp += __shfl_xor(dp, 4, 64);
          bl[tb][r] += dp;                            // identical across c8
        }
      } else {
        if (t < 8) {                                  // g=0, c8=t
          float2 o; o.x = fac * s0; o.y = fac * s1;
          *reinterpret_cast<float2*>(out + ((size_t)(b0 + tb) * kJ + j) * kC + t * 2) = o;
        }
      }
    }
    // Parity buffering makes iter k+1's sred writes race-free against iter
    // k's reads; one __syncthreads per iteration suffices.
  }
}

}  // namespace

extern "C" void kernel_launch(void* const* d_in, const int* in_sizes, int n_in,
                              void* d_out, int out_size, void* d_ws, size_t ws_size,
                              hipStream_t stream) {
  (void)in_sizes; (void)n_in; (void)d_ws; (void)ws_size; (void)out_size;
  const float* x = reinterpret_cast<const float*>(d_in[0]);
  const float* W = reinterpret_cast<const float*>(d_in[1]);
  float* out = reinterpret_cast<float*>(d_out);
  const int grid = (kB / TB) * kJ;  // 2560 blocks, j-major
  digitcaps_fused<<<grid, THREADS, 0, stream>>>(x, W, out);
}

// Round 11
// 245.565 us; speedup vs baseline: 1.3652x; 1.3652x over previous
//
#include <hip/hip_runtime.h>
#include <math.h>

namespace {

constexpr int kB = 512, kI = 1152, kD = 8, kJ = 10, kC = 16;
constexpr int THREADS = 768;                // 12 waves, 1 block/CU (LDS-capped)
constexpr int TB = 2;                       // batches per block (shares W loads)
constexpr int GRP = THREADS / 4;            // 192 i-groups; 4 threads (c4) per i
constexpr int ROWS = kI / GRP;              // 6 rows per thread
constexpr int NW = THREADS / 64;            // 12 waves
constexpr float EPS = 1e-7f;

// Thread (g = t>>2, c4 = t&3) owns i-rows {g + 192*r} and channels
// {4c4..4c4+3}. x_hat lives in LDS in exactly this layout; every LDS and
// global access is float4 (round 9's float2 regression: halving vector width
// doubles instruction count and loses more than occupancy gains).
//
// Round-8 -> round-10 deltas (both validated separately):
//  - 768 threads: same block count / same W L2-traffic / same 147 KB LDS,
//    but 12 waves hiding phase-1's ~200-cycle L2 latency (was 8).
//  - no softmax max-subtraction (round 9 verified: b bounded by |v||xhat|<6,
//    absmax 2.4e-7) + parity-buffered scratch -> 1 barrier per iteration.
__launch_bounds__(THREADS)
__global__ void digitcaps_fused(const float* __restrict__ x,
                                const float* __restrict__ W,
                                float* __restrict__ out) {
  __shared__ float xhat[TB][kI][kC];        // 147,456 B
  __shared__ float sredS[2][TB][NW][kC];    // 3,072 B (parity-buffered)
  __shared__ float sredZ[2][TB][NW];        // 192 B

  const int t    = threadIdx.x;
  const int lane = t & 63;
  const int wid  = t >> 6;
  const int c4   = t & 3;
  const int g    = t >> 2;                  // 0..191

  const int bid = blockIdx.x;
  const int j   = bid >> 8;                 // j-major: 256 blocks share W[j] in L2
  const int b0  = (bid & 255) * TB;

  // ---------------- Phase 1: x_hat[b,j,i,c] = sum_d x[b,i,d]*W[j,i,d,c] -----
  #pragma unroll 3
  for (int it = 0; it < ROWS; ++it) {
    const int i = it * GRP + g;
    const float* Wp = W + (size_t)(j * kI + i) * (kD * kC) + (c4 << 2);
    float xr[TB][kD];
    #pragma unroll
    for (int tb = 0; tb < TB; ++tb) {
      const float4* xp = reinterpret_cast<const float4*>(
          x + (size_t)((b0 + tb) * kI + i) * kD);
      const float4 v0 = xp[0], v1 = xp[1];
      xr[tb][0] = v0.x; xr[tb][1] = v0.y; xr[tb][2] = v0.z; xr[tb][3] = v0.w;
      xr[tb][4] = v1.x; xr[tb][5] = v1.y; xr[tb][6] = v1.z; xr[tb][7] = v1.w;
    }
    float a[TB][4] = {};
    #pragma unroll
    for (int d = 0; d < kD; ++d) {
      const float4 w = *reinterpret_cast<const float4*>(Wp + d * kC);
      #pragma unroll
      for (int tb = 0; tb < TB; ++tb) {
        a[tb][0] += xr[tb][d] * w.x;
        a[tb][1] += xr[tb][d] * w.y;
        a[tb][2] += xr[tb][d] * w.z;
        a[tb][3] += xr[tb][d] * w.w;
      }
    }
    #pragma unroll
    for (int tb = 0; tb < TB; ++tb) {
      float4 v4;
      v4.x = a[tb][0]; v4.y = a[tb][1]; v4.z = a[tb][2]; v4.w = a[tb][3];
      *reinterpret_cast<float4*>(&xhat[tb][i][c4 * 4]) = v4;
    }
  }
  __syncthreads();                          // phase-1 -> phase-2

  // ---------------- Phase 2: 3 routing iterations, 1 barrier each -----------
  float bl[TB][ROWS];                       // logits; identical across c4 lanes
  #pragma unroll
  for (int tb = 0; tb < TB; ++tb)
    #pragma unroll
    for (int r = 0; r < ROWS; ++r) bl[tb][r] = 0.f;

  #pragma unroll
  for (int itr = 0; itr < 3; ++itr) {
    const int p = itr & 1;

    // --- partial Z and s over own rows/channels (no max: exp args bounded) ---
    float zp[TB], sp[TB][4];
    #pragma unroll
    for (int tb = 0; tb < TB; ++tb) {
      zp[tb] = 0.f; sp[tb][0] = sp[tb][1] = sp[tb][2] = sp[tb][3] = 0.f;
      #pragma unroll
      for (int r = 0; r < ROWS; ++r) {
        const int i = r * GRP + g;
        const float4 h = *reinterpret_cast<const float4*>(&xhat[tb][i][c4 * 4]);
        const float e = expf(bl[tb][r]);
        zp[tb]    += e;
        sp[tb][0] += e * h.x; sp[tb][1] += e * h.y;
        sp[tb][2] += e * h.z; sp[tb][3] += e * h.w;
      }
    }
    #pragma unroll
    for (int off = 4; off < 64; off <<= 1) {          // reduce over g in wave
      #pragma unroll
      for (int tb = 0; tb < TB; ++tb) {
        zp[tb]    += __shfl_xor(zp[tb],    off, 64);
        sp[tb][0] += __shfl_xor(sp[tb][0], off, 64);
        sp[tb][1] += __shfl_xor(sp[tb][1], off, 64);
        sp[tb][2] += __shfl_xor(sp[tb][2], off, 64);
        sp[tb][3] += __shfl_xor(sp[tb][3], off, 64);
      }
    }
    if (lane < 4) {                                   // lane == c4 partial
      #pragma unroll
      for (int tb = 0; tb < TB; ++tb) {
        float4 v4;
        v4.x = sp[tb][0]; v4.y = sp[tb][1]; v4.z = sp[tb][2]; v4.w = sp[tb][3];
        *reinterpret_cast<float4*>(&sredS[p][tb][wid][lane * 4]) = v4;
      }
    }
    if (lane == 0) {
      #pragma unroll
      for (int tb = 0; tb < TB; ++tb) sredZ[p][tb][wid] = zp[tb];
    }
    __syncthreads();                                  // the iteration's barrier

    // --- combine wave partials; squash; agreement or final write ---
    #pragma unroll
    for (int tb = 0; tb < TB; ++tb) {
      float Z = 0.f;
      #pragma unroll
      for (int w = 0; w < NW; ++w) Z += sredZ[p][tb][w];
      float s0 = 0.f, s1 = 0.f, s2 = 0.f, s3 = 0.f;
      #pragma unroll
      for (int w = 0; w < NW; ++w) {                  // broadcast reads
        const float4 v4 = *reinterpret_cast<const float4*>(&sredS[p][tb][w][c4 * 4]);
        s0 += v4.x; s1 += v4.y; s2 += v4.z; s3 += v4.w;
      }
      const float invZ = 1.f / Z;
      s0 *= invZ; s1 *= invZ; s2 *= invZ; s3 *= invZ;
      float pq = s0 * s0 + s1 * s1 + s2 * s2 + s3 * s3;
      pq += __shfl_xor(pq, 1, 64);                    // sum |s|^2 across c4
      pq += __shfl_xor(pq, 2, 64);
      const float nrm = sqrtf(pq);
      const float fac = pq / ((1.f + pq) * (nrm + EPS));

      if (itr < 2) {
        const float vc0 = fac * s0, vc1 = fac * s1, vc2 = fac * s2, vc3 = fac * s3;
        #pragma unroll
        for (int r = 0; r < ROWS; ++r) {
          const int i = r * GRP + g;
          const float4 h = *reinterpret_cast<const float4*>(&xhat[tb][i][c4 * 4]);
          float dp = vc0 * h.x + vc1 * h.y + vc2 * h.z + vc3 * h.w;
          dp += __shfl_xor(dp, 1, 64);                // sum across c4 (same g)
          dp += __shfl_xor(dp, 2, 64);
          bl[tb][r] += dp;                            // identical across c4
        }
      } else {
        if (t < 4) {                                  // g=0, c4=t
          float4 o;
          o.x = fac * s0; o.y = fac * s1; o.z = fac * s2; o.w = fac * s3;
          *reinterpret_cast<float4*>(out + ((size_t)(b0 + tb) * kJ + j) * kC + t * 4) = o;
        }
      }
    }
    // Parity buffering: iter k's post-barrier reads of sred[p] are separated
    // from iter k+2's writes to sred[p] by barrier k+1 -> race-free with one
    // __syncthreads per iteration.
  }
}

}  // namespace

extern "C" void kernel_launch(void* const* d_in, const int* in_sizes, int n_in,
                              void* d_out, int out_size, void* d_ws, size_t ws_size,
                              hipStream_t stream) {
  (void)in_sizes; (void)n_in; (void)d_ws; (void)ws_size; (void)out_size;
  const float* x = reinterpret_cast<const float*>(d_in[0]);
  const float* W = reinterpret_cast<const float*>(d_in[1]);
  float* out = reinterpret_cast<float*>(d_out);
  const int grid = (kB / TB) * kJ;  // 2560 blocks, j-major
  digitcaps_fused<<<grid, THREADS, 0, stream>>>(x, W, out);
}

// Round 12
// 183.154 us; speedup vs baseline: 1.8304x; 1.3408x over previous
//
#include <hip/hip_runtime.h>
#include <math.h>

namespace {

constexpr int kB = 512, kI = 1152, kD = 8, kJ = 10, kC = 16;
constexpr int THREADS = 512;             // 8 waves
constexpr int GRP = THREADS / 4;         // 128 i-groups; 4 threads (c4) per i
constexpr int ROWS = kI / GRP;           // 9 rows per thread
constexpr int NW = THREADS / 64;         // 8 waves
constexpr float EPS = 1e-7f;

// Round-12 design (from round-11 post-mortem: phase 2 is LDS/shuffle-pipe
// bound, and 147 KB LDS means no cross-block overlap):
//  - TB=1, LDS 74.3 KB -> 2 blocks/CU: block n+1's phase 1 (memory) overlaps
//    block n's phase 2 (LDS pipe).
//  - Routing fused: pass0 = plain row-sum (softmax(0) is uniform -> no exp,
//    no Z); pass1/2 fuse the agreement update into the Z-pass -> xhat is
//    streamed 3x total instead of 6x.
//  - Combine via 16 reducer threads + vfac broadcast: each thread reads ONE
//    b128 of v per pass instead of 24 broadcast reads. Pass 2's reducer
//    writes the output directly.
//  - __expf (2 inst) instead of expf; absmax headroom is ~38x.
__launch_bounds__(THREADS)
__global__ void digitcaps_fused(const float* __restrict__ x,
                                const float* __restrict__ W,
                                float* __restrict__ out) {
  __shared__ float xhat[kI][kC];         // 73,728 B
  __shared__ float sredS[NW][kC];        // 512 B per-wave s partials
  __shared__ float sredZ[NW];            // 32 B
  __shared__ float vfac[kC];             // 64 B: v = fac * s (broadcast)

  const int t    = threadIdx.x;
  const int lane = t & 63;
  const int wid  = t >> 6;
  const int c4   = t & 3;
  const int g    = t >> 2;               // 0..127

  const int bid = blockIdx.x;
  const int j   = bid >> 9;              // j-major: 512 blocks share W[j] in L2
  const int b   = bid & 511;

  // ---------------- Phase 1: x_hat[i][c] = sum_d x[b,i,d] * W[j,i,d,c] ------
  #pragma unroll 3
  for (int it = 0; it < ROWS; ++it) {
    const int i = it * GRP + g;
    const float* Wp = W + (size_t)(j * kI + i) * (kD * kC) + (c4 << 2);
    const float4* xp = reinterpret_cast<const float4*>(x + (size_t)(b * kI + i) * kD);
    const float4 v0 = xp[0], v1 = xp[1];
    float xr[kD] = {v0.x, v0.y, v0.z, v0.w, v1.x, v1.y, v1.z, v1.w};
    float a0 = 0.f, a1 = 0.f, a2 = 0.f, a3 = 0.f;
    #pragma unroll
    for (int d = 0; d < kD; ++d) {
      const float4 w = *reinterpret_cast<const float4*>(Wp + d * kC);
      a0 += xr[d] * w.x; a1 += xr[d] * w.y;
      a2 += xr[d] * w.z; a3 += xr[d] * w.w;
    }
    float4 v4; v4.x = a0; v4.y = a1; v4.z = a2; v4.w = a3;
    *reinterpret_cast<float4*>(&xhat[i][c4 * 4]) = v4;
  }
  __syncthreads();

  // ---------------- Phase 2: 3 fused routing passes -------------------------
  float bl[ROWS];
  #pragma unroll
  for (int r = 0; r < ROWS; ++r) bl[r] = 0.f;

  #pragma unroll
  for (int pass = 0; pass < 3; ++pass) {
    float4 vv;
    if (pass > 0)                        // v from previous pass (one b128)
      vv = *reinterpret_cast<const float4*>(&vfac[c4 * 4]);

    float zp = 0.f, sp0 = 0.f, sp1 = 0.f, sp2 = 0.f, sp3 = 0.f;
    #pragma unroll
    for (int r = 0; r < ROWS; ++r) {
      const int i = r * GRP + g;
      const float4 h = *reinterpret_cast<const float4*>(&xhat[i][c4 * 4]);
      if (pass == 0) {
        // softmax(0) is uniform: c_i = 1/kI -> plain row sum, no exp.
        sp0 += h.x; sp1 += h.y; sp2 += h.z; sp3 += h.w;
      } else {
        // fused agreement + softmax-numerator accumulate
        float dp = vv.x * h.x + vv.y * h.y + vv.z * h.z + vv.w * h.w;
        dp += __shfl_xor(dp, 1, 64);     // sum across c4 (same row)
        dp += __shfl_xor(dp, 2, 64);
        bl[r] += dp;
        const float e = __expf(bl[r]);   // b bounded: |b| <= 2|v||xhat| < 6
        zp  += e;
        sp0 += e * h.x; sp1 += e * h.y; sp2 += e * h.z; sp3 += e * h.w;
      }
    }
    #pragma unroll
    for (int off = 4; off < 64; off <<= 1) {   // reduce over g within wave
      sp0 += __shfl_xor(sp0, off, 64);
      sp1 += __shfl_xor(sp1, off, 64);
      sp2 += __shfl_xor(sp2, off, 64);
      sp3 += __shfl_xor(sp3, off, 64);
      if (pass > 0) zp += __shfl_xor(zp, off, 64);
    }
    if (lane < 4) {                            // lane == c4 holds its partial
      float4 v4; v4.x = sp0; v4.y = sp1; v4.z = sp2; v4.w = sp3;
      *reinterpret_cast<float4*>(&sredS[wid][lane * 4]) = v4;
    }
    if (pass > 0 && lane == 0) sredZ[wid] = zp;
    __syncthreads();                           // partials ready

    // --- reducer: 16 threads combine, squash, publish v (or write out) ---
    if (t < kC) {
      float sr = 0.f;
      #pragma unroll
      for (int w = 0; w < NW; ++w) sr += sredS[w][t];
      float Z;
      if (pass == 0) {
        Z = (float)kI;
      } else {
        Z = 0.f;
        #pragma unroll
        for (int w = 0; w < NW; ++w) Z += sredZ[w];  // broadcast reads
      }
      const float sc = sr / Z;
      float pq = sc * sc;
      pq += __shfl_xor(pq, 1, 64);               // |s|^2 over 16 lanes
      pq += __shfl_xor(pq, 2, 64);
      pq += __shfl_xor(pq, 4, 64);
      pq += __shfl_xor(pq, 8, 64);
      const float nrm = sqrtf(pq);
      const float fac = pq / ((1.f + pq) * (nrm + EPS));
      const float vc = fac * sc;                 // v[t]
      if (pass < 2) vfac[t] = vc;
      else out[((size_t)b * kJ + j) * kC + t] = vc;
    }
    __syncthreads();                             // vfac ready / sredS reusable
    // Races: sredS/Z written pre-B1, read by reducer pre-B2, rewritten next
    // pass post-B2. vfac read at pass start (pre-B1), written by reducer
    // post-B1 of the SAME pass? No: reducer writes pass k's vfac between B1
    // and B2 of pass k; pass k+1 reads it after B2. Safe.
  }
}

}  // namespace

extern "C" void kernel_launch(void* const* d_in, const int* in_sizes, int n_in,
                              void* d_out, int out_size, void* d_ws, size_t ws_size,
                              hipStream_t stream) {
  (void)in_sizes; (void)n_in; (void)d_ws; (void)ws_size; (void)out_size;
  const float* x = reinterpret_cast<const float*>(d_in[0]);
  const float* W = reinterpret_cast<const float*>(d_in[1]);
  float* out = reinterpret_cast<float*>(d_out);
  const int grid = kB * kJ;  // 5120 blocks, j-major
  digitcaps_fused<<<grid, THREADS, 0, stream>>>(x, W, out);
}